// Round 7
// baseline (590.362 us; speedup 1.0000x reference)
//
#include <hip/hip_runtime.h>
#include <stdint.h>

// Problem constants (B=32, D=256, H=32, W=32, K=2048)
#define K_CODES 2048
#define DIM 256
#define NROWS 32768            // B*H*W
#define ROWS_PER_BLOCK 32
#define THREADS 1024           // 16 waves: 2 row-halves x 8 code-groups
#define HW_STRIDE 1024         // H*W
#define QLOSS_OFFSET 8388608
#define PROB_OFFSET 8388609ULL
#define ZB_PITCH 264           // ushorts per LDS z-row: 256 + 8 pad
#define EP_PITCH 2052          // fp16 per prob row: 2048 + 4 pad
#define NBLOCKS (NROWS / ROWS_PER_BLOCK)   // 1024
#define CPX (NBLOCKS / 8)                  // 128 blocks per XCD chunk

typedef short v8s __attribute__((ext_vector_type(8)));   // 8 bf16 (MFMA operand)
typedef float v4f __attribute__((ext_vector_type(4)));
typedef float v2f __attribute__((ext_vector_type(2)));
typedef __fp16 v2h __attribute__((ext_vector_type(2)));

__device__ __forceinline__ ushort f2bf(float x) {
    uint32_t u = __float_as_uint(x);
    return (ushort)((u + 0x7FFFu + ((u >> 16) & 1u)) >> 16);   // RNE
}

// Prep: codebook fp32 -> bf16 (ws), cnorm[k] = sum c^2, zero the q_loss slot.
__global__ void prep_kernel(const float* __restrict__ cb, ushort* __restrict__ cbb,
                            float* __restrict__ cnorm, float* __restrict__ qloss) {
    const int code = blockIdx.x;
    const int lane = threadIdx.x;     // 64 threads
    float4 v = ((const float4*)(cb + code * DIM))[lane];
    ushort4 o;
    o.x = f2bf(v.x); o.y = f2bf(v.y); o.z = f2bf(v.z); o.w = f2bf(v.w);
    ((ushort4*)(cbb + code * DIM))[lane] = o;
    float ss = v.x * v.x + v.y * v.y + v.z * v.z + v.w * v.w;
    #pragma unroll
    for (int m = 32; m >= 1; m >>= 1) ss += __shfl_xor(ss, m, 64);
    if (lane == 0) cnorm[code] = ss;
    if (code == 0 && lane == 0) *qloss = 0.f;
}

// 16 waves/block, 4 waves/EU -> 1 block/CU (128-reg budget). LDS ~148 KB.
__launch_bounds__(THREADS, 4)
__global__ void vq_kernel(const float* __restrict__ z, const float* __restrict__ cb,
                          const ushort* __restrict__ cbb, const float* __restrict__ cnorm,
                          float* __restrict__ out) {
    // eplds: fp16 exp matrix [32 rows][2052] = 131.3 KB. Its first 32 KB doubles
    // as the fp32 z staging area (zf) before the ct-loop starts writing exps.
    __shared__ __align__(16) ushort eplds[ROWS_PER_BLOCK * EP_PITCH];
    __shared__ ushort zb[ROWS_PER_BLOCK * ZB_PITCH];     // [m][k] bf16, padded (16.9 KB)
    __shared__ float red_sum[8][32];
    __shared__ float red_val[8][32];
    __shared__ int   red_code[8][32];
    __shared__ float row_sum[32];
    __shared__ int   row_idx[32];
    __shared__ float lred[16];

    const int t = threadIdx.x;
    // XCD-chunk swizzle (bijective: 1024 % 8 == 0).
    const int bid = ((int)blockIdx.x & 7) * CPX + ((int)blockIdx.x >> 3);
    const int n0 = bid * ROWS_PER_BLOCK;                 // first global row (32-aligned)
    const int bb = n0 >> 10;                             // batch index
    const int hw = n0 & 1023;                            // 32-aligned h*w offset
    const float* zbase = z + (size_t)bb * (DIM * HW_STRIDE) + hw;

    float* zf = (float*)eplds;                           // alias (pre-loop only), [d][m=32]

    // ---- stage z -> zf [d][32]; full 128B lines per d-row; keep own vals in zrf ----
    float zrf[8];
    #pragma unroll
    for (int j = 0; j < 2; ++j) {
        int i4 = t + j * THREADS;                        // 0..2047
        int d = i4 >> 3, m0 = (i4 & 7) << 2;
        float4 v = *(const float4*)(zbase + (size_t)d * HW_STRIDE + m0);
        zrf[4 * j + 0] = v.x; zrf[4 * j + 1] = v.y;
        zrf[4 * j + 2] = v.z; zrf[4 * j + 3] = v.w;
        *(float4*)&zf[d * 32 + m0] = v;
    }
    __syncthreads();
    // ---- transpose zf -> zb bf16 [m][k] for MFMA A-fragments ----
    #pragma unroll
    for (int j = 0; j < 4; ++j) {
        int i2 = t + j * THREADS;                        // 0..4095
        int m = i2 & 31, kp = i2 >> 5;                   // kp = k/2, 0..127
        float a0 = zf[(2 * kp) * 32 + m];
        float a1 = zf[(2 * kp + 1) * 32 + m];
        uint32_t pk = (uint32_t)f2bf(a0) | ((uint32_t)f2bf(a1) << 16);
        *(uint32_t*)&zb[m * ZB_PITCH + 2 * kp] = pk;
    }
    __syncthreads();
    // zf region dead from here; ct-loop writes exps into eplds.

    const int wave = t >> 6, lane = t & 63;
    const int rowHalf = wave >> 3;                       // 0: rows 0-15, 1: rows 16-31
    const int wgrp = wave & 7;                           // code group
    const int q = lane >> 4, lm = lane & 15;
    const int c0 = wgrp * 256;                           // this wave's code range
    const int r0 = rowHalf * 16;                         // this wave's row base

    // A fragments: lane holds A[m = r0+lm][k = ks*32 + q*8 + j], all 8 k-steps
    v8s afrag[8];
    const ushort* arow = &zb[(r0 + lm) * ZB_PITCH + q * 8];
    #pragma unroll
    for (int ks = 0; ks < 8; ++ks) afrag[ks] = *(const v8s*)(arow + ks * 32);

    // K-loop: 16 col-tiles x 8 k-steps, software-pipelined one tile deep.
    // Per-wave structure identical to the proven 16-row kernel.
    const ushort* bptr = cbb + (size_t)(c0 + lm) * DIM + q * 8;  // code = c0+ct*16+lm
    v8s bb0[8];
    #pragma unroll
    for (int ks = 0; ks < 8; ++ks) bb0[ks] = *(const v8s*)(bptr + ks * 32);
    float cn0 = cnorm[c0 + lm];

    __fp16* epf = (__fp16*)eplds;
    float sume[4] = {0.f, 0.f, 0.f, 0.f};
    float bval[4] = {-1e30f, -1e30f, -1e30f, -1e30f};
    int   bcode[4] = {0, 0, 0, 0};
    #pragma unroll
    for (int ct = 0; ct < 16; ++ct) {
        v8s bb1[8];
        float cn1;
        if (ct < 15) {
            const ushort* np = bptr + (size_t)(ct + 1) * (16 * DIM);
            #pragma unroll
            for (int ks = 0; ks < 8; ++ks) bb1[ks] = *(const v8s*)(np + ks * 32);
            cn1 = cnorm[c0 + (ct + 1) * 16 + lm];
        }
        v4f a = {0.f, 0.f, 0.f, 0.f};
        #pragma unroll
        for (int ks = 0; ks < 8; ++ks)
            a = __builtin_amdgcn_mfma_f32_16x16x32_bf16(afrag[ks], bb0[ks], a, 0, 0, 0);
        const int code = c0 + ct * 16 + lm;
        #pragma unroll
        for (int r = 0; r < 4; ++r) {
            float l = 2.f * a[r] - cn0;                  // logit = 2 z.c - |c|^2 (|z|^2 cancels)
            float ev = __expf(l);
            sume[r] += ev;
            if (l > bval[r]) { bval[r] = l; bcode[r] = code; }
            epf[(r0 + q * 4 + r) * EP_PITCH + code] = (__fp16)ev;
        }
        cn0 = cn1;
        #pragma unroll
        for (int ks = 0; ks < 8; ++ks) bb0[ks] = bb1[ks];  // renamed away (full unroll)
    }
    // butterfly across the 16 lanes (lm) of each quad-row group
    #pragma unroll
    for (int m = 1; m <= 8; m <<= 1) {
        #pragma unroll
        for (int r = 0; r < 4; ++r) {
            sume[r] += __shfl_xor(sume[r], m, 64);
            float v2 = __shfl_xor(bval[r], m, 64);
            int   c2 = __shfl_xor(bcode[r], m, 64);
            if (v2 > bval[r] || (v2 == bval[r] && c2 < bcode[r])) { bval[r] = v2; bcode[r] = c2; }
        }
    }
    if (lm == 0) {
        #pragma unroll
        for (int r = 0; r < 4; ++r) {
            red_sum[wgrp][r0 + q * 4 + r]  = sume[r];    // row-halves write disjoint rows
            red_val[wgrp][r0 + q * 4 + r]  = bval[r];
            red_code[wgrp][r0 + q * 4 + r] = bcode[r];
        }
    }
    __syncthreads();
    if (t < 32) {
        float s = 0.f, bv = -1e30f;
        int bc = 0;
        #pragma unroll
        for (int w = 0; w < 8; ++w) {
            s += red_sum[w][t];
            float v = red_val[w][t];
            int   c = red_code[w][t];
            if (v > bv || (v == bv && c < bc)) { bv = v; bc = c; }
        }
        row_sum[t] = s;
        row_idx[t] = bc;
    }
    __syncthreads();

    // ---- z_q gather: issue codebook loads early; complete under the store stream ----
    float cv[8];
    #pragma unroll
    for (int j = 0; j < 2; ++j) {
        int i4 = t + j * THREADS;
        int d = i4 >> 3, m0 = (i4 & 7) << 2;
        #pragma unroll
        for (int i = 0; i < 4; ++i) cv[4 * j + i] = cb[row_idx[m0 + i] * DIM + d];
    }

    // ---- distance_prob: LDS-transposed coalesced stream (v2f per thread/row) ----
    float* prob = out + PROB_OFFSET;
    #pragma unroll
    for (int rr = 0; rr < ROWS_PER_BLOCK; ++rr) {
        float rs = 1.f / row_sum[rr];                    // wave-uniform broadcast
        v2h e = *(const v2h*)&epf[rr * EP_PITCH + t * 2];
        v2f o = { e[0] * rs, e[1] * rs };
        *(v2f*)(prob + (size_t)(n0 + rr) * K_CODES + t * 2) = o;
    }

    // ---- z_q store (full 128B lines per d-row) + q_loss ----
    float lacc = 0.f;
    #pragma unroll
    for (int j = 0; j < 2; ++j) {
        int i4 = t + j * THREADS;
        int d = i4 >> 3, m0 = (i4 & 7) << 2;
        float ov[4];
        #pragma unroll
        for (int i = 0; i < 4; ++i) {
            float cvv = cv[4 * j + i];
            float df = zrf[4 * j + i] - cvv;
            lacc += df * df;
            ov[i] = cvv;
        }
        v4f o4 = {ov[0], ov[1], ov[2], ov[3]};
        *(v4f*)(out + (size_t)bb * (DIM * HW_STRIDE) + hw + (size_t)d * HW_STRIDE + m0) = o4;
    }
    #pragma unroll
    for (int m = 32; m >= 1; m >>= 1) lacc += __shfl_xor(lacc, m, 64);
    if (lane == 0) lred[wave] = lacc;
    __syncthreads();
    if (t == 0) {
        float s = 0.f;
        #pragma unroll
        for (int w = 0; w < 16; ++w) s += lred[w];
        // q_loss = (1 + BETA) * mean((z_q - z)^2); both loss terms coincide in fwd
        atomicAdd(out + QLOSS_OFFSET, s * (1.25f / 8388608.f));
    }
}

extern "C" void kernel_launch(void* const* d_in, const int* in_sizes, int n_in,
                              void* d_out, int out_size, void* d_ws, size_t ws_size,
                              hipStream_t stream) {
    const float* z  = (const float*)d_in[0];   // (32,256,32,32) fp32
    const float* cb = (const float*)d_in[1];   // (2048,256) fp32
    float* out = (float*)d_out;
    ushort* cbb  = (ushort*)d_ws;                                  // bf16 codebook, 1 MB
    float*  cnm  = (float*)((char*)d_ws + (size_t)K_CODES * DIM * sizeof(ushort));
    prep_kernel<<<K_CODES, 64, 0, stream>>>(cb, cbb, cnm, out + QLOSS_OFFSET);
    vq_kernel<<<NBLOCKS, THREADS, 0, stream>>>(z, cb, cbb, cnm, out);
}